// Round 10
// baseline (159.445 us; speedup 1.0000x reference)
//
#include <hip/hip_runtime.h>
#include <math.h>

// Problem constants (MultiHeadAttention_15341623181946)
#define NB 8          // batch
#define SS 1024       // sequence
#define NH 16         // heads
#define DK 64         // head dim
#define EE 1024       // NH*DK
#define DMOD 1024     // d_model

using bf16x8 = __attribute__((ext_vector_type(8))) short;   // 8 bf16 = 4 VGPR
using f32x4  = __attribute__((ext_vector_type(4))) float;   // MFMA acc

__device__ __forceinline__ unsigned short f2bf(float f) {
    unsigned u = __builtin_bit_cast(unsigned, f);
    u += 0x7FFFu + ((u >> 16) & 1u);        // round-to-nearest-even
    return (unsigned short)(u >> 16);
}

__device__ __forceinline__ float exp2_hw(float x) {
#if __has_builtin(__builtin_amdgcn_exp2f)
    return __builtin_amdgcn_exp2f(x);
#else
    float r; asm("v_exp_f32 %0, %1" : "=v"(r) : "v"(x)); return r;
#endif
}

__device__ __forceinline__ unsigned cvt_pk_bf16(float lo, float hi) {
    unsigned r;
    asm("v_cvt_pk_bf16_f32 %0, %1, %2" : "=v"(r) : "v"(lo), "v"(hi));
    return r;
}

// Async global->LDS, 16B per lane. LDS dest must be wave-uniform base;
// HW writes base + lane*16. Global src is per-lane.
__device__ __forceinline__ void gld16(const void* g, void* l) {
    __builtin_amdgcn_global_load_lds(
        (const __attribute__((address_space(1))) void*)g,
        (__attribute__((address_space(3))) void*)l, 16, 0, 0);
}

// ---------------------------------------------------------------------------
// f32 -> bf16 conversion: z = 0:W1(1M) 1:W2(1M) 2:Wq(64K). grid (512, 3).
// ---------------------------------------------------------------------------
__global__ __launch_bounds__(256) void cvt_w(
    const float* __restrict__ W1, const float* __restrict__ W2,
    const float* __restrict__ Wq,
    unsigned short* __restrict__ W1b, unsigned short* __restrict__ W2b,
    unsigned short* __restrict__ Wqb)
{
    const int z = blockIdx.y;
    const float* s; unsigned short* d; int n;
    switch (z) {
        case 0:  s = W1; d = W1b; n = 1048576; break;
        case 1:  s = W2; d = W2b; n = 1048576; break;
        default: s = Wq; d = Wqb; n = 65536;   break;
    }
    const int i = (blockIdx.x * 256 + threadIdx.x) * 8;
    if (i >= n) return;
    const float4 a = *(const float4*)(s + i);
    const float4 b = *(const float4*)(s + i + 4);
    bf16x8 o;
    o[0]=(short)f2bf(a.x); o[1]=(short)f2bf(a.y); o[2]=(short)f2bf(a.z); o[3]=(short)f2bf(a.w);
    o[4]=(short)f2bf(b.x); o[5]=(short)f2bf(b.y); o[6]=(short)f2bf(b.z); o[7]=(short)f2bf(b.w);
    *(bf16x8*)(d + i) = o;
}

// ---------------------------------------------------------------------------
// Projection GEMM, bf16 MFMA, K=64. z = 0:q (scaled), 1:k, 2:v (TRANSPOSED).
// z<2 : C[b][h][s][d]  = (X @ Wq^T + bq) * sc
// z==2: C[b][h][d][s]  =  X @ Wq^T + bq        (V stored pre-transposed)
// A is staged from f32 with inline bf16 cvt (reg->LDS); Wq via gld16.
// Epilogue goes through a padded LDS tile (reusing staging LDS) so ALL
// global stores are contiguous 128B runs (fixes the z==2 d-scatter).
// ---------------------------------------------------------------------------
#define OTP 136   // out-tile LDS pitch (ushorts): 68 dwords == 4 mod 32
__global__ __launch_bounds__(256) void proj_mfma(
    const float* __restrict__ qf32, const float* __restrict__ kf32,
    const float* __restrict__ vf32, const unsigned short* __restrict__ Wb,
    const float* __restrict__ bias, unsigned short* __restrict__ Cbase,
    float qscale)
{
    __shared__ __align__(16) unsigned short Sh[128 * OTP];  // 34816 B
    unsigned short* As = Sh;                // [128][64] linear (staging)
    unsigned short* Bs = Sh + 8192;
    const int z = blockIdx.z;
    const float* X = (z == 0) ? qf32 : (z == 1) ? kf32 : vf32;
    unsigned short* C = Cbase + (size_t)z * 8388608;
    const float sc = (z == 0) ? qscale : 1.0f;
    const int tid  = threadIdx.x;
    const int lane = tid & 63;
    const int w = tid >> 6, wm = w >> 1, wn = w & 1;
    const int n0 = blockIdx.x * 128, m0 = blockIdx.y * 128;
    const int lr = lane & 15, lg = lane >> 4;

    // stage: A from f32 (reg cvt), B via async gld16
    #pragma unroll
    for (int p = 0; p < 4; ++p) {
        const int c = p * 256 + tid;               // chunk 0..1023
        const int row = c >> 3, col = (c & 7) * 8;
        const int lb = (p * 256 + (tid & ~63)) * 8;
        gld16(Wb + (size_t)n0 * DK + (size_t)c * 8, Bs + lb);
        const float4 a = *(const float4*)(X + (size_t)(m0 + row) * DK + col);
        const float4 b = *(const float4*)(X + (size_t)(m0 + row) * DK + col + 4);
        bf16x8 o;
        o[0]=(short)f2bf(a.x); o[1]=(short)f2bf(a.y); o[2]=(short)f2bf(a.z); o[3]=(short)f2bf(a.w);
        o[4]=(short)f2bf(b.x); o[5]=(short)f2bf(b.y); o[6]=(short)f2bf(b.z); o[7]=(short)f2bf(b.w);
        *(bf16x8*)&As[row * 64 + col] = o;
    }
    __syncthreads();

    f32x4 acc[4][4] = {};
    #pragma unroll
    for (int kk = 0; kk < 2; ++kk) {
        bf16x8 af[4], bfr[4];
        #pragma unroll
        for (int mf = 0; mf < 4; ++mf)
            af[mf] = *(const bf16x8*)&As[(wm * 64 + mf * 16 + lr) * 64 + kk * 32 + lg * 8];
        #pragma unroll
        for (int nf = 0; nf < 4; ++nf)
            bfr[nf] = *(const bf16x8*)&Bs[(wn * 64 + nf * 16 + lr) * 64 + kk * 32 + lg * 8];
        #pragma unroll
        for (int mf = 0; mf < 4; ++mf)
            #pragma unroll
            for (int nf = 0; nf < 4; ++nf)
                acc[mf][nf] = __builtin_amdgcn_mfma_f32_16x16x32_bf16(
                    af[mf], bfr[nf], acc[mf][nf], 0, 0, 0);
    }

    __syncthreads();   // staging reads done -> reuse Sh as out-tile

    // acc -> LDS out tile. z<2: Ot[m_local][n_local]; z==2: Ot[n_local][m_local]
    #pragma unroll
    for (int nf = 0; nf < 4; ++nf) {
        const int nl = wn * 64 + nf * 16 + lr;
        const float bb = bias[n0 + nl];
        #pragma unroll
        for (int mf = 0; mf < 4; ++mf)
            #pragma unroll
            for (int r = 0; r < 4; ++r) {
                const int ml = wm * 64 + mf * 16 + lg * 4 + r;
                const unsigned short v = f2bf((acc[mf][nf][r] + bb) * sc);
                if (z == 2) Sh[nl * OTP + ml] = v;
                else        Sh[ml * OTP + nl] = v;
            }
    }
    __syncthreads();

    // coalesced store: thread = (row, half); 64 contiguous ushorts each
    const int row = tid >> 1, half = tid & 1;
    unsigned short* dst;
    if (z == 2) {
        const int n = n0 + row;                       // n -> (h, d)
        const int bh = (m0 >> 10) * NH + (n >> 6);
        dst = C + (size_t)bh * 65536 + (size_t)(n & 63) * 1024
                + (m0 & 1023) + half * 64;
    } else {
        const int mr = m0 + row;                      // m -> (b, s)
        const int bh = (mr >> 10) * NH + ((n0 + half * 64) >> 6);
        dst = C + (size_t)bh * 65536 + (size_t)(mr & 1023) * 64;
    }
    const unsigned short* srcr = &Sh[row * OTP + half * 64];
    #pragma unroll
    for (int j = 0; j < 8; ++j)
        *(bf16x8*)(dst + j * 8) = *(const bf16x8*)(srcr + j * 8);
}

// ---------------------------------------------------------------------------
// Flash attention v10: R9 body (verified) with KVBLK=128 as TWO 64-k
// sub-chunks per LDS tile-pair: barriers halve (32 -> 16), prefetch window
// doubles. Same 2-barrier publish pattern, T2 chunk-XOR swizzle, swapped
// QK^T, base-2 softmax, defer-max, XCD swizzle. 32 q-rows/wave (QBLK=128).
// ---------------------------------------------------------------------------
__global__ __launch_bounds__(256) void attn_v10(
    const unsigned short* __restrict__ Qp, const unsigned short* __restrict__ Kp,
    const unsigned short* __restrict__ Vt, unsigned short* __restrict__ Y)
{
    __shared__ __align__(16) unsigned short Ks[2][64 * 64];   // [sub]
    __shared__ __align__(16) unsigned short Vs[2][64 * 64];   // rows d, cols k
    __shared__ __align__(16) unsigned short Ps[4][32][72];    // per-wave P [q][k]
    const int tid  = threadIdx.x;
    const int lane = tid & 63;
    const int w    = tid >> 6;
    // ---- bijective XCD swizzle: 1024 blocks, 128/XCD, (b,h) contiguous ----
    const int flat    = blockIdx.x;                 // 0..1023
    const int logical = (flat & 7) * 128 + (flat >> 3);
    const int qt = logical & 7;                     // q-tile 0..7 (128 rows)
    const int bh = logical >> 3;                    // 0..127
    const int q0 = qt * 128;
    const size_t base = (size_t)bh * (SS * DK);
    const int lr = lane & 15, lg = lane >> 4;
    const int lg4 = lg * 4;

    // staging geometry: two 16B chunks per thread per sub-tile
    const int c0 = tid,       r0 = c0 >> 3, h0 = c0 & 7;
    const int c1 = 256 + tid, r1 = c1 >> 3, h1 = c1 & 7;
    const int lds0 = r0 * 64 + ((h0 ^ (r0 & 7)) << 3);   // swizzled ushort idx
    const int lds1 = r1 * 64 + ((h1 ^ (r1 & 7)) << 3);

    const unsigned short* kbase = Kp + base;
    const unsigned short* vbase = Vt + base;

    // ---- tile-pair 0 (subs 0,1) -> regs -> LDS ----
    #pragma unroll
    for (int sub = 0; sub < 2; ++sub) {
        const int sb = sub * 64;
        *(bf16x8*)&Ks[sub][lds0] = *(const bf16x8*)(kbase + (size_t)(sb + r0) * DK + h0 * 8);
        *(bf16x8*)&Ks[sub][lds1] = *(const bf16x8*)(kbase + (size_t)(sb + r1) * DK + h1 * 8);
        *(bf16x8*)&Vs[sub][lds0] = *(const bf16x8*)(vbase + (size_t)r0 * SS + sb + h0 * 8);
        *(bf16x8*)&Vs[sub][lds1] = *(const bf16x8*)(vbase + (size_t)r1 * SS + sb + h1 * 8);
    }

    // ---- Q fragments direct from global (loop-invariant), 2 q-groups ----
    bf16x8 bQ[2][2];
    #pragma unroll
    for (int qf = 0; qf < 2; ++qf) {
        const unsigned short* qptr =
            Qp + base + (size_t)(q0 + w * 32 + qf * 16 + lr) * DK + lg * 8;
        bQ[qf][0] = *(const bf16x8*)qptr;
        bQ[qf][1] = *(const bf16x8*)(qptr + 32);
    }

    __syncthreads();

    float m[2] = {-1e30f, -1e30f}, l[2] = {0.0f, 0.0f};
    f32x4 oacc[2][4] = {};            // [qf][d0], row r -> q = qf*16+lg4+r
    bf16x8 kPA[2], kPB[2], vPA[2], vPB[2];

    for (int kt = 0; kt < 8; ++kt) {
        // --- T14: issue next tile-pair's global loads before compute ---
        if (kt < 7) {
            #pragma unroll
            for (int sub = 0; sub < 2; ++sub) {
                const int sb = (kt + 1) * 128 + sub * 64;
                kPA[sub] = *(const bf16x8*)(kbase + (size_t)(sb + r0) * DK + h0 * 8);
                kPB[sub] = *(const bf16x8*)(kbase + (size_t)(sb + r1) * DK + h1 * 8);
                vPA[sub] = *(const bf16x8*)(vbase + (size_t)r0 * SS + sb + h0 * 8);
                vPB[sub] = *(const bf16x8*)(vbase + (size_t)r1 * SS + sb + h1 * 8);
            }
        }

        #pragma unroll
        for (int sub = 0; sub < 2; ++sub) {
            // --- QK^T (swapped) for both q-groups ---
            f32x4 sacc[2][4];
            #pragma unroll
            for (int nb = 0; nb < 4; ++nb) {
                const int krow = nb * 16 + lr;
                const bf16x8 aK0 = *(const bf16x8*)&Ks[sub][krow * 64 + ((lg       ^ (lr & 7)) << 3)];
                const bf16x8 aK1 = *(const bf16x8*)&Ks[sub][krow * 64 + (((4 + lg) ^ (lr & 7)) << 3)];
                #pragma unroll
                for (int qf = 0; qf < 2; ++qf) {
                    f32x4 z = {};
                    z = __builtin_amdgcn_mfma_f32_16x16x32_bf16(aK0, bQ[qf][0], z, 0, 0, 0);
                    z = __builtin_amdgcn_mfma_f32_16x16x32_bf16(aK1, bQ[qf][1], z, 0, 0, 0);
                    sacc[qf][nb] = z;
                }
            }

            // --- V fragments (read once, feed both PV halves) ---
            bf16x8 bV[2][4];
            #pragma unroll
            for (int kk = 0; kk < 2; ++kk)
                #pragma unroll
                for (int d0 = 0; d0 < 4; ++d0) {
                    const int vrow = d0 * 16 + lr;
                    bV[kk][d0] = *(const bf16x8*)&Vs[sub][vrow * 64 + (((kk * 4 + lg) ^ (lr & 7)) << 3)];
                }

            // --- per-group online softmax + PV ---
            #pragma unroll
            for (int qf = 0; qf < 2; ++qf) {
                float mx = sacc[qf][0][0];
                #pragma unroll
                for (int nb = 0; nb < 4; ++nb)
                    #pragma unroll
                    for (int r = 0; r < 4; ++r)
                        mx = fmaxf(mx, sacc[qf][nb][r]);
                mx = fmaxf(mx, __shfl_xor(mx, 16));
                mx = fmaxf(mx, __shfl_xor(mx, 32));

                if (__any(mx > m[qf] + 8.0f)) {    // T13 defer-max, THR=8
                    const float mn = fmaxf(m[qf], mx);
                    const float alpha = exp2_hw(m[qf] - mn);
                    m[qf] = mn;
                    l[qf] *= alpha;
                    #pragma unroll
                    for (int r = 0; r < 4; ++r) {
                        const float ar = __shfl(alpha, lg4 + r, 16);
                        #pragma unroll
                        for (int d0 = 0; d0 < 4; ++d0) oacc[qf][d0][r] *= ar;
                    }
                }

                float p[4][4];
                float ls = 0.0f;
                #pragma unroll
                for (int nb = 0; nb < 4; ++nb)
                    #pragma unroll
                    for (int r = 0; r < 4; ++r) {
                        const float pv = exp2_hw(sacc[qf][nb][r] - m[qf]);
                        p[nb][r] = pv;
                        ls += pv;
                    }
                ls += __shfl_xor(ls, 16);
                ls += __shfl_xor(ls, 32);
                l[qf] += ls;

                // pack P -> LDS rows qf*16 + q
                #pragma unroll
                for (int nb = 0; nb < 4; ++nb) {
                    uint2 pw;
                    pw.x = cvt_pk_bf16(p[nb][0], p[nb][1]);
                    pw.y = cvt_pk_bf16(p[nb][2], p[nb][3]);
                    *(uint2*)&Ps[w][qf * 16 + lr][nb * 16 + lg4] = pw;
                }
                // same-wave write->read: in-order LDS + compiler lgkmcnt

                // PV: O[16q][64d] += P[16][64] x V[64][64]
                #pragma unroll
                for (int kk = 0; kk < 2; ++kk) {
                    const bf16x8 aP = *(const bf16x8*)&Ps[w][qf * 16 + lr][kk * 32 + lg * 8];
                    #pragma unroll
                    for (int d0 = 0; d0 < 4; ++d0)
                        oacc[qf][d0] = __builtin_amdgcn_mfma_f32_16x16x32_bf16(
                            aP, bV[kk][d0], oacc[qf][d0], 0, 0, 0);
                }
            }
        }

        // --- publish prefetched tile-pair (2-barrier pattern, verified) ---
        if (kt < 7) {
            __syncthreads();                   // all waves done reading tiles
            #pragma unroll
            for (int sub = 0; sub < 2; ++sub) {
                *(bf16x8*)&Ks[sub][lds0] = kPA[sub]; *(bf16x8*)&Ks[sub][lds1] = kPB[sub];
                *(bf16x8*)&Vs[sub][lds0] = vPA[sub]; *(bf16x8*)&Vs[sub][lds1] = vPB[sub];
            }
            __syncthreads();                   // tiles ready
        }
    }

    // epilogue: Y[b][s][h*64+d] bf16; 1/l broadcast per row
    const int hh = bh & 15, bb = bh >> 4;
    #pragma unroll
    for (int qf = 0; qf < 2; ++qf) {
        const float linv = 1.0f / l[qf];
        #pragma unroll
        for (int r = 0; r < 4; ++r) {
            const float lri = __shfl(linv, lg4 + r, 16);
            const int qr = q0 + w * 32 + qf * 16 + lg4 + r;
            unsigned short* dst = Y + (size_t)(bb * SS + qr) * EE + hh * DK;
            #pragma unroll
            for (int d0 = 0; d0 < 4; ++d0)
                dst[d0 * 16 + lr] = f2bf(oacc[qf][d0][r] * lri);
        }
    }
}

// ---------------------------------------------------------------------------
// MLP GEMM, bf16 MFMA, m97-structure: C = A[M,K] @ B[N,K]^T + bias (+ReLU)
// 128x128 tile, 4 waves (2x2 of 64x64), K-step 64, LINEAR LDS staged via
// global_load_lds width=16. 1D grid + bijective XCD swizzle (A-tile L2 reuse).
// ---------------------------------------------------------------------------
template<bool RELU, bool OUT_BF16>
__global__ __launch_bounds__(256) void mlp_gemm(
    const unsigned short* __restrict__ A, const unsigned short* __restrict__ B,
    const float* __restrict__ bias, void* __restrict__ Cv)
{
    constexpr int K = 1024, N = 1024;
    __shared__ __align__(16) unsigned short As[128 * 64];
    __shared__ __align__(16) unsigned short Bs[128 * 64];
    const int tid  = threadIdx.x;
    const int lane = tid & 63;
    const int w = tid >> 6, wm = w >> 1, wn = w & 1;
    // bijective XCD swizzle: 512 blocks, 64/XCD = 8 M-tiles x 8 N-tiles
    const int flat    = blockIdx.x;
    const int logical = (flat & 7) * 64 + (flat >> 3);
    const int n0 = (logical & 7) * 128, m0 = (logical >> 3) * 128;
    const int lr = lane & 15, lg = lane >> 4;

    f32x4 acc[4][4] = {};

    for (int kt = 0; kt < K; kt += 64) {
        __syncthreads();                       // previous tile's readers done
        #pragma unroll
        for (int p = 0; p < 4; ++p) {
            const int c = p * 256 + tid;       // chunk 0..1023
            const int row = c >> 3, col = (c & 7) * 8;
            const int lb = (p * 256 + (tid & ~63)) * 8;   // wave-uniform LDS base
            gld16(A + (size_t)(m0 + row) * K + kt + col, As + lb);
            gld16(B + (size_t)(n0 + row) * K + kt + col, Bs + lb);
        }
        __syncthreads();                       // vmcnt(0) drain + publish
        #pragma unroll
        for (int kk = 0; kk < 2; ++kk) {
            bf16x8 af[4], bfr[4];
            #pragma unroll
            for (int mf = 0; mf < 4; ++mf)
                af[mf] = *(const bf16x8*)&As[(wm * 64 + mf * 16 + lr) * 64 + kk * 32 + lg * 8];
            #pragma unroll
            for (int nf = 0; nf < 4; ++nf)
                bfr[nf] = *(const bf16x8*)&Bs[(wn * 64 + nf * 16 + lr) * 64 + kk * 32 + lg * 8];
            #pragma unroll
            for (int mf = 0; mf < 4; ++mf)
                #pragma unroll
                for (int nf = 0; nf < 4; ++nf)
                    acc[mf][nf] = __builtin_amdgcn_mfma_f32_16x16x32_bf16(
                        af[mf], bfr[nf], acc[mf][nf], 0, 0, 0);
        }
    }

    #pragma unroll
    for (int nf = 0; nf < 4; ++nf) {
        const int cc = n0 + wn * 64 + nf * 16 + lr;
        const float bb = bias[cc];
        #pragma unroll
        for (int mf = 0; mf < 4; ++mf) {
            #pragma unroll
            for (int r = 0; r < 4; ++r) {
                float x = acc[mf][nf][r] + bb;
                if (RELU) x = fmaxf(x, 0.0f);
                const size_t rr = (size_t)(m0 + wm * 64 + mf * 16 + lg * 4 + r);
                if (OUT_BF16) ((unsigned short*)Cv)[rr * N + cc] = f2bf(x);
                else          ((float*)Cv)[rr * N + cc] = x;
            }
        }
    }
}

// ---------------------------------------------------------------------------
// Workspace layout (ushort elements):
//   Qp : [0        , 8388608 )  -> reused as H1 after attention
//   Kp : [8388608  , 16777216)
//   Vt : [16777216 , 25165824)  (projection z=2 writes [b][h][d][s] directly)
//   Y  : [25165824 , 33554432)
//   W1b: [33554432 , 34603008)
//   W2b: [34603008 , 35651584)
//   Wqb: [35651584 , 35717120)   total ~71.4 MB
// ---------------------------------------------------------------------------
extern "C" void kernel_launch(void* const* d_in, const int* in_sizes, int n_in,
                              void* d_out, int out_size, void* d_ws, size_t ws_size,
                              hipStream_t stream) {
    const float* q  = (const float*)d_in[0];
    const float* k  = (const float*)d_in[1];
    const float* v  = (const float*)d_in[2];
    const float* Wq = (const float*)d_in[3];
    const float* bq = (const float*)d_in[4];
    const float* W1 = (const float*)d_in[5];
    const float* b1 = (const float*)d_in[6];
    const float* W2 = (const float*)d_in[7];
    const float* b2 = (const float*)d_in[8];

    unsigned short* wsu = (unsigned short*)d_ws;
    unsigned short* Qp  = wsu;
    unsigned short* Kp  = wsu + (size_t)8388608;
    unsigned short* Vt  = wsu + (size_t)16777216;
    unsigned short* Y   = wsu + (size_t)25165824;
    unsigned short* W1b = wsu + (size_t)33554432;
    unsigned short* W2b = wsu + (size_t)34603008;
    unsigned short* Wqb = wsu + (size_t)35651584;
    unsigned short* H1  = Qp;   // Qp dead after attention

    dim3 blk(256);

    cvt_w<<<dim3(512, 3), blk, 0, stream>>>(W1, W2, Wq, W1b, W2b, Wqb);

    // folds 1/sqrt(dk)=0.125 and log2(e) into Q so attn uses v_exp_f32 directly
    const float qscale = 0.125f * 1.44269504088896340736f;
    proj_mfma<<<dim3(8, 64, 3), blk, 0, stream>>>(q, k, v, Wqb, bq, Qp, qscale);

    attn_v10<<<1024, blk, 0, stream>>>(Qp, Kp, Vt, Y);

    mlp_gemm<true,  true ><<<512, blk, 0, stream>>>(Y,  W1b, b1, H1);
    mlp_gemm<false, false><<<512, blk, 0, stream>>>(H1, W2b, b2, d_out);
}